// Round 5
// baseline (220.605 us; speedup 1.0000x reference)
//
#include <hip/hip_runtime.h>

#define PITCH 72   // bf16 pitch for MFMA planes: 144 B rows, 16B-aligned

typedef __attribute__((ext_vector_type(8))) short short8v;
typedef __attribute__((ext_vector_type(4))) short short4v;
typedef __attribute__((ext_vector_type(4))) float f32x4;

// ---------------- bf16 split helpers -----------------------------------------
__device__ __forceinline__ short f2bf(float v) {
    unsigned u = __builtin_bit_cast(unsigned, v);
    unsigned r = (u + 0x7FFFu + ((u >> 16) & 1u)) >> 16;
    return (short)r;
}
__device__ __forceinline__ float bf2f(short s) {
    unsigned u = ((unsigned)(unsigned short)s) << 16;
    return __builtin_bit_cast(float, u);
}

#define MFMA(a, b, c) __builtin_amdgcn_mfma_f32_16x16x32_bf16(a, b, c, 0, 0, 0)

// A/B fragment from LDS plane (pitch 72)
__device__ __forceinline__ short8v ldfrag(const short* p, int rowtile, int kc, int l) {
    return *(const short8v*)&p[(rowtile * 16 + (l & 15)) * PITCH + kc * 32 + (l >> 4) * 8];
}
// fragment from global row-major [rows][64]
__device__ __forceinline__ short8v gfrag(const short* __restrict__ p, int rowtile, int kc, int l) {
    return *(const short8v*)&p[(rowtile * 16 + (l & 15)) * 64 + kc * 32 + (l >> 4) * 8];
}

// D = X·Y^T split-3; X,Y in LDS; wave w owns D row-tile w, 4 col-tiles
__device__ __forceinline__ void p3(const short* xh, const short* xl,
                                   const short* yh, const short* yl,
                                   int w, int l, f32x4 (&acc)[4]) {
#pragma unroll
    for (int ct = 0; ct < 4; ++ct) acc[ct] = (f32x4){0.f, 0.f, 0.f, 0.f};
#pragma unroll
    for (int kc = 0; kc < 2; ++kc) {
        short8v aH = ldfrag(xh, w, kc, l);
        short8v aL = ldfrag(xl, w, kc, l);
#pragma unroll
        for (int ct = 0; ct < 4; ++ct) {
            short8v bH = ldfrag(yh, ct, kc, l);
            short8v bL = ldfrag(yl, ct, kc, l);
            acc[ct] = MFMA(aH, bH, acc[ct]);
            acc[ct] = MFMA(aH, bL, acc[ct]);
            acc[ct] = MFMA(aL, bH, acc[ct]);
        }
    }
}

// D = X·Y^T split-3; X hi/lo from GLOBAL row-major [64][64]
__device__ __forceinline__ void p3_ga(const short* __restrict__ xgh,
                                      const short* __restrict__ xgl,
                                      const short* yh, const short* yl,
                                      int w, int l, f32x4 (&acc)[4]) {
#pragma unroll
    for (int ct = 0; ct < 4; ++ct) acc[ct] = (f32x4){0.f, 0.f, 0.f, 0.f};
#pragma unroll
    for (int kc = 0; kc < 2; ++kc) {
        short8v aH = gfrag(xgh, w, kc, l);
        short8v aL = gfrag(xgl, w, kc, l);
#pragma unroll
        for (int ct = 0; ct < 4; ++ct) {
            short8v bH = ldfrag(yh, ct, kc, l);
            short8v bL = ldfrag(yl, ct, kc, l);
            acc[ct] = MFMA(aH, bH, acc[ct]);
            acc[ct] = MFMA(aH, bL, acc[ct]);
            acc[ct] = MFMA(aL, bH, acc[ct]);
        }
    }
}

// D = X·Y^T, X hi-only from GLOBAL row-major [64][64]
__device__ __forceinline__ void p2v_g(const short* __restrict__ xg,
                                      const short* yh, const short* yl,
                                      int w, int l, f32x4 (&acc)[4]) {
#pragma unroll
    for (int ct = 0; ct < 4; ++ct) acc[ct] = (f32x4){0.f, 0.f, 0.f, 0.f};
#pragma unroll
    for (int kc = 0; kc < 2; ++kc) {
        short8v aH = gfrag(xg, w, kc, l);
#pragma unroll
        for (int ct = 0; ct < 4; ++ct) {
            short8v bH = ldfrag(yh, ct, kc, l);
            short8v bL = ldfrag(yl, ct, kc, l);
            acc[ct] = MFMA(aH, bH, acc[ct]);
            acc[ct] = MFMA(aH, bL, acc[ct]);
        }
    }
}

// pack-store D transposed with hi/lo split: z[n][m] = D[m][n]
__device__ __forceinline__ void pack_store(const f32x4 (&acc)[4],
                                           short* zh, short* zl, int w, int l) {
    int m0 = w * 16 + (l >> 4) * 4;
#pragma unroll
    for (int ct = 0; ct < 4; ++ct) {
        int n = ct * 16 + (l & 15);
        short4v h, lo;
#pragma unroll
        for (int r = 0; r < 4; ++r) {
            float v = acc[ct][r];
            short hb = f2bf(v);
            h[r]  = hb;
            lo[r] = f2bf(v - bf2f(hb));
        }
        *(short4v*)&zh[n * PITCH + m0] = h;
        *(short4v*)&zl[n * PITCH + m0] = lo;
    }
}

// in-place exact transpose of TWO planes via identity-MFMA (1 internal barrier)
__device__ __forceinline__ void idtrans_ip2(short* pa, short* pb, int w, int l) {
    short8v a0 = ldfrag(pa, w, 0, l);
    short8v a1 = ldfrag(pa, w, 1, l);
    short8v b0 = ldfrag(pb, w, 0, l);
    short8v b1 = ldfrag(pb, w, 1, l);
    short8v I0, I1;
#pragma unroll
    for (int j = 0; j < 8; ++j) {
        int bit = 8 * (l >> 4) + j;
        I0[j] = (bit == (l & 15))      ? (short)0x3F80 : (short)0;
        I1[j] = (bit == (l & 15) + 16) ? (short)0x3F80 : (short)0;
    }
    __syncthreads();
    int m0 = w * 16 + (l >> 4) * 4;
    const f32x4 z4 = {0.f, 0.f, 0.f, 0.f};
#pragma unroll
    for (int s = 0; s < 4; ++s) {
        f32x4 d = MFMA((s >> 1) ? a1 : a0, (s & 1) ? I1 : I0, z4);
        f32x4 e = MFMA((s >> 1) ? b1 : b0, (s & 1) ? I1 : I0, z4);
        short4v ha, hb2;
#pragma unroll
        for (int r = 0; r < 4; ++r) { ha[r] = f2bf(d[r]); hb2[r] = f2bf(e[r]); }
        int drow = s * 16 + (l & 15);
        *(short4v*)&pa[drow * PITCH + m0] = ha;
        *(short4v*)&pb[drow * PITCH + m0] = hb2;
    }
}

// ---------------- K0: inv_diag ------------------------------------------------
__global__ __launch_bounds__(256) void k0_invdiag(const float* __restrict__ x,
                                                  float* __restrict__ invd) {
    int t = blockIdx.x * 256 + threadIdx.x;
    int nc = t >> 6, k = t & 63;
    float v = fabsf(x[(size_t)nc * 4096 + (size_t)k * 65]);
    invd[t] = rsqrtf(fmaxf(v, 1e-4f));
}

// ---------------- K0b: w3T[co][c] = concat(wq,wk,wv)^T, bf16 hi/lo ------------
__global__ __launch_bounds__(256) void k0b_w3(const float* __restrict__ wq,
                                              const float* __restrict__ wk,
                                              const float* __restrict__ wv,
                                              short* __restrict__ w3h,
                                              short* __restrict__ w3l) {
    int idx = blockIdx.x * 256 + threadIdx.x;   // [0, 12288)
    int co = idx >> 6, c = idx & 63;
    const float* w = (co < 64) ? wq : (co < 128) ? wk : wv;
    float v = w[c * 64 + (co & 63)];
    short h = f2bf(v);
    w3h[idx] = h;
    w3l[idx] = f2bf(v - bf2f(h));
}

// ---------------- K1: cov2cor + channel mixing via MFMA -----------------------
// Block (n,i): D[j][co] = sum_c cor[c][j] * W[c][co]; direct reg->global stores
__global__ __launch_bounds__(256, 6) void k1_mix_mfma(
    const float* __restrict__ x, const float* __restrict__ invd,
    const short* __restrict__ w3h, const short* __restrict__ w3l,
    short* __restrict__ Qio,                       // d_out: per-nc 16KB slots (hi|lo)
    short* __restrict__ Kh, short* __restrict__ Kl, short* __restrict__ Vh)
{
    __shared__ __align__(16) short ch[4608];       // cor hi  [64][72]
    __shared__ __align__(16) short cl[4608];       // cor lo

    const int b = blockIdx.x, n = b >> 6, i = b & 63;
    const int t = threadIdx.x, l = t & 63, w = t >> 6;
    const size_t nbase = (size_t)n * 64;

    // stage cor hi/lo planes [c][j]
#pragma unroll
    for (int rep = 0; rep < 4; ++rep) {
        int id = rep * 256 + t;                 // 1024 float4 chunks
        int c = id >> 4, j4 = (id & 15) * 4;
        float4 xv = *(const float4*)&x[((nbase + c) * 64 + i) * 64 + j4];
        float ii = invd[(nbase + c) * 64 + i];
        float4 jv = *(const float4*)&invd[(nbase + c) * 64 + j4];
        float vv[4] = {xv.x * ii * jv.x, xv.y * ii * jv.y,
                       xv.z * ii * jv.z, xv.w * ii * jv.w};
        short4v h, lo;
#pragma unroll
        for (int r = 0; r < 4; ++r) {
            float v = fminf(1.0f, fmaxf(-1.0f, vv[r]));
            short hb = f2bf(v);
            h[r]  = hb;
            lo[r] = f2bf(v - bf2f(hb));
        }
        *(short4v*)&ch[c * PITCH + j4] = h;
        *(short4v*)&cl[c * PITCH + j4] = lo;
    }
    __syncthreads();
    idtrans_ip2(ch, cl, w, l);     // cor -> corT in place (1 internal barrier)
    __syncthreads();

    // wave w: co-tiles ct = 3w..3w+2, all 4 j-tiles; split-3
    f32x4 acc[4][3];
#pragma unroll
    for (int jt = 0; jt < 4; ++jt)
#pragma unroll
        for (int cc = 0; cc < 3; ++cc) acc[jt][cc] = (f32x4){0.f, 0.f, 0.f, 0.f};
#pragma unroll
    for (int kc = 0; kc < 2; ++kc) {
#pragma unroll
        for (int cc = 0; cc < 3; ++cc) {
            short8v bH = gfrag(w3h, w * 3 + cc, kc, l);
            short8v bL = gfrag(w3l, w * 3 + cc, kc, l);
#pragma unroll
            for (int jt = 0; jt < 4; ++jt) {
                short8v aH = ldfrag(ch, jt, kc, l);
                short8v aL = ldfrag(cl, jt, kc, l);
                acc[jt][cc] = MFMA(aH, bH, acc[jt][cc]);
                acc[jt][cc] = MFMA(aH, bL, acc[jt][cc]);
                acc[jt][cc] = MFMA(aL, bH, acc[jt][cc]);
            }
        }
    }

    // direct reg->global stores (transposed pack): z[co][jt*16+m0..+3]
    {
        const int m0 = (l >> 4) * 4, nb = l & 15;
#pragma unroll
        for (int cc = 0; cc < 3; ++cc) {
            int r16 = w * 3 + cc;            // 16-row tile id, wave-uniform
            int corow = r16 * 16 + nb;
#pragma unroll
            for (int jt = 0; jt < 4; ++jt) {
                int col = jt * 16 + m0;
                short4v h;
#pragma unroll
                for (int r = 0; r < 4; ++r) h[r] = f2bf(acc[jt][cc][r]);
                if (r16 < 4) {
                    short4v lo;
#pragma unroll
                    for (int r = 0; r < 4; ++r) {
                        float v = acc[jt][cc][r];
                        lo[r] = f2bf(v - bf2f(f2bf(v)));
                    }
                    size_t base = (nbase + corow) * 8192 + (size_t)i * 64 + col;
                    *(short4v*)&Qio[base] = h;
                    *(short4v*)&Qio[base + 4096] = lo;
                } else if (r16 < 8) {
                    short4v lo;
#pragma unroll
                    for (int r = 0; r < 4; ++r) {
                        float v = acc[jt][cc][r];
                        lo[r] = f2bf(v - bf2f(f2bf(v)));
                    }
                    size_t base = (nbase + corow - 64) * 4096 + (size_t)i * 64 + col;
                    *(short4v*)&Kh[base] = h;
                    *(short4v*)&Kl[base] = lo;
                } else {
                    size_t base = (nbase + corow - 128) * 4096 + (size_t)i * 64 + col;
                    *(short4v*)&Vh[base] = h;
                }
            }
        }
    }
}

// ---------------- K2: per-(n,c) attention chain (split-bf16 MFMA) -------------
__global__ __launch_bounds__(256, 4) void k2_attn_mfma(
    const float* __restrict__ x,
    const short* __restrict__ Qio,
    const short* __restrict__ Kh, const short* __restrict__ Kl,
    const short* __restrict__ Vh,
    float* __restrict__ out)
{
    // P0 Z1h->z4h ; P1 Z1l->z4l ; P2 Kh->Kth->Ah ; P3 Kl->Ktl->Al
    __shared__ __align__(16) short planes[4][4608];
    __shared__ float part[4][64];
    __shared__ float invs[64];
    __shared__ float red[4];

    const int t = threadIdx.x, l = t & 63, w = t >> 6;
    const int nc = blockIdx.x;
    const size_t gbase = (size_t)nc * 4096;

    const short* qh = Qio + (size_t)nc * 8192;
    const short* ql = qh + 4096;
    const short* kh = Kh + gbase;
    const short* kl = Kl + gbase;
    const short* vh = Vh + gbase;

    // stage K hi/lo only
#pragma unroll
    for (int rep = 0; rep < 4; ++rep) {
        int id = rep * 256 + t;
        int r = id >> 4, c4 = (id & 15) * 4;
        *(short4v*)&planes[2][r * PITCH + c4] = *(const short4v*)&kh[r * 64 + c4];
        *(short4v*)&planes[3][r * PITCH + c4] = *(const short4v*)&kl[r * 64 + c4];
    }
    __syncthreads();

    idtrans_ip2(planes[2], planes[3], w, l);   // K -> Kt in place
    __syncthreads();

    f32x4 acc[4];

    // Z1 = Q(global) · Kt^T  -> pack into P0,P1 (untouched so far; no barrier)
    p3_ga(qh, ql, planes[2], planes[3], w, l, acc);
    pack_store(acc, planes[0], planes[1], w, l);
    __syncthreads();

    // Pt = Z1 · Kt^T (in registers)
    p3(planes[0], planes[1], planes[2], planes[3], w, l, acc);

    // ---- soft_pd_max ----
    float mx = -1e30f;
#pragma unroll
    for (int ct = 0; ct < 4; ++ct)
#pragma unroll
        for (int r = 0; r < 4; ++r) mx = fmaxf(mx, acc[ct][r]);
#pragma unroll
    for (int off = 1; off < 64; off <<= 1) mx = fmaxf(mx, __shfl_xor(mx, off));
    if (l == 0) red[w] = mx;
    __syncthreads();
    mx = fmaxf(fmaxf(red[0], red[1]), fmaxf(red[2], red[3]));

    float e[4][4];
    float cs[4];
#pragma unroll
    for (int ct = 0; ct < 4; ++ct) {
        float s = 0.f;
#pragma unroll
        for (int r = 0; r < 4; ++r) {
            float ev = __expf(acc[ct][r] - mx);
            e[ct][r] = ev;
            s += ev;
        }
        cs[ct] = s;
    }
#pragma unroll
    for (int ct = 0; ct < 4; ++ct) {
        cs[ct] += __shfl_xor(cs[ct], 16);
        cs[ct] += __shfl_xor(cs[ct], 32);
    }
    if (l < 16) {
#pragma unroll
        for (int ct = 0; ct < 4; ++ct) part[w][ct * 16 + l] = cs[ct];
    }
    __syncthreads();
    if (t < 64) {
        float dia = part[0][t] + part[1][t] + part[2][t] + part[3][t];
        float tot = dia;
#pragma unroll
        for (int off = 1; off < 64; off <<= 1) tot += __shfl_xor(tot, off);
        dia = fmaxf(dia, tot / 100000.0f);
        dia = fmaxf(dia, 1e-5f);
        invs[t] = rsqrtf(dia);
    }
    __syncthreads();

    // A[m][n] = e*inv*inv -> P2,P3 (Kt dead; softmax barriers fence M2 reads)
    {
        int m0 = w * 16 + (l >> 4) * 4;
        float ir[4] = {invs[m0], invs[m0 + 1], invs[m0 + 2], invs[m0 + 3]};
        int nb = l & 15;
#pragma unroll
        for (int ct = 0; ct < 4; ++ct) {
            float ic = invs[ct * 16 + nb];
            short4v h, lo;
#pragma unroll
            for (int r = 0; r < 4; ++r) {
                float v = e[ct][r] * ir[r] * ic;
                short hb = f2bf(v);
                h[r]  = hb;
                lo[r] = f2bf(v - bf2f(hb));
            }
            *(short4v*)&planes[2][(ct * 16 + nb) * PITCH + m0] = h;
            *(short4v*)&planes[3][(ct * 16 + nb) * PITCH + m0] = lo;
        }
    }
    __syncthreads();

    // z4 = V(global) · A^T  -> pack into P0,P1 (Z1 dead since softmax barriers)
    p2v_g(vh, planes[2], planes[3], w, l, acc);
    pack_store(acc, planes[0], planes[1], w, l);
    __syncthreads();

    // OUT = A · z4^T = A V A^T
    p3(planes[2], planes[3], planes[0], planes[1], w, l, acc);
    __syncthreads();   // all reads of P0..P3 done; alias as f32 out-stage

    // stage out tile f32 [64][68] over planes, then vectorized residual+store
    {
        float* ofs = (float*)&planes[0][0];
        int m0 = w * 16 + (l >> 4) * 4;
        int nb = l & 15;
#pragma unroll
        for (int ct = 0; ct < 4; ++ct)
#pragma unroll
            for (int r = 0; r < 4; ++r)
                ofs[(m0 + r) * 68 + ct * 16 + nb] = acc[ct][r];
    }
    __syncthreads();
    {
        const float* ofs = (const float*)&planes[0][0];
#pragma unroll
        for (int rep = 0; rep < 4; ++rep) {
            int id = rep * 256 + t;
            int row = id >> 4, c4 = (id & 15) * 4;
            float4 v  = *(const float4*)&ofs[row * 68 + c4];
            float4 xv = *(const float4*)&x[gbase + (size_t)row * 64 + c4];
            *(float4*)&out[gbase + (size_t)row * 64 + c4] =
                make_float4(xv.x + v.x, xv.y + v.y, xv.z + v.z, xv.w + v.w);
        }
    }
}

// ---------------- launch -----------------------------------------------------
extern "C" void kernel_launch(void* const* d_in, const int* in_sizes, int n_in,
                              void* d_out, int out_size, void* d_ws, size_t ws_size,
                              hipStream_t stream) {
    const float* x  = (const float*)d_in[0];
    const float* wq = (const float*)d_in[1];
    const float* wk = (const float*)d_in[2];
    const float* wv = (const float*)d_in[3];
    float* out = (float*)d_out;

    char* wsb = (char*)d_ws;
    float* invd = (float*)wsb;                       // 1 MB
    short* w3h  = (short*)(wsb + (1 << 20));         // 24 KB
    short* w3l  = w3h + 12288;                       // 24 KB
    short* Kh   = (short*)(wsb + (2 << 20));         // 32 MB
    short* Kl   = Kh + 16777216;                     // 32 MB
    short* Vh   = Kl + 16777216;                     // 32 MB
    short* Qio  = (short*)d_out;                     // per-nc 16KB (hi|lo) slots

    k0_invdiag<<<1024, 256, 0, stream>>>(x, invd);
    k0b_w3<<<48, 256, 0, stream>>>(wq, wk, wv, w3h, w3l);
    k1_mix_mfma<<<4096, 256, 0, stream>>>(x, invd, w3h, w3l, Qio, Kh, Kl, Vh);
    k2_attn_mfma<<<4096, 256, 0, stream>>>(x, Qio, Kh, Kl, Vh, out);
}

// Round 6
// 88.021 us; speedup vs baseline: 2.5063x; 2.5063x over previous
//
#include <hip/hip_runtime.h>

#define PITCH 72   // bf16 pitch for MFMA planes: 144 B rows, 16B-aligned

typedef __attribute__((ext_vector_type(8))) short short8v;
typedef __attribute__((ext_vector_type(4))) short short4v;
typedef __attribute__((ext_vector_type(4))) float f32x4;

// ---------------- bf16 helpers -----------------------------------------------
__device__ __forceinline__ short f2bf(float v) {
    unsigned u = __builtin_bit_cast(unsigned, v);
    unsigned r = (u + 0x7FFFu + ((u >> 16) & 1u)) >> 16;
    return (short)r;
}
__device__ __forceinline__ float bf2f(short s) {
    unsigned u = ((unsigned)(unsigned short)s) << 16;
    return __builtin_bit_cast(float, u);
}

#define MFMA(a, b, c) __builtin_amdgcn_mfma_f32_16x16x32_bf16(a, b, c, 0, 0, 0)

// A/B fragment from LDS plane (pitch 72)
__device__ __forceinline__ short8v ldfrag(const short* p, int rowtile, int kc, int l) {
    return *(const short8v*)&p[(rowtile * 16 + (l & 15)) * PITCH + kc * 32 + (l >> 4) * 8];
}
// fragment from global row-major [rows][64]
__device__ __forceinline__ short8v gfrag(const short* __restrict__ p, int rowtile, int kc, int l) {
    return *(const short8v*)&p[(rowtile * 16 + (l & 15)) * 64 + kc * 32 + (l >> 4) * 8];
}

// D = X·Y^T, hi-only, X,Y in LDS
__device__ __forceinline__ void p1(const short* xh, const short* yh,
                                   int w, int l, f32x4 (&acc)[4]) {
#pragma unroll
    for (int ct = 0; ct < 4; ++ct) acc[ct] = (f32x4){0.f, 0.f, 0.f, 0.f};
#pragma unroll
    for (int kc = 0; kc < 2; ++kc) {
        short8v aH = ldfrag(xh, w, kc, l);
#pragma unroll
        for (int ct = 0; ct < 4; ++ct)
            acc[ct] = MFMA(aH, ldfrag(yh, ct, kc, l), acc[ct]);
    }
}

// D = X·Y^T, hi-only, X from GLOBAL [64][64]
__device__ __forceinline__ void p1_g(const short* __restrict__ xg, const short* yh,
                                     int w, int l, f32x4 (&acc)[4]) {
#pragma unroll
    for (int ct = 0; ct < 4; ++ct) acc[ct] = (f32x4){0.f, 0.f, 0.f, 0.f};
#pragma unroll
    for (int kc = 0; kc < 2; ++kc) {
        short8v aH = gfrag(xg, w, kc, l);
#pragma unroll
        for (int ct = 0; ct < 4; ++ct)
            acc[ct] = MFMA(aH, ldfrag(yh, ct, kc, l), acc[ct]);
    }
}

// D = X·Y^T, X hi-only GLOBAL, Y split hi/lo in LDS  (z4 = V·A^T)
__device__ __forceinline__ void p2v_g(const short* __restrict__ xg,
                                      const short* yh, const short* yl,
                                      int w, int l, f32x4 (&acc)[4]) {
#pragma unroll
    for (int ct = 0; ct < 4; ++ct) acc[ct] = (f32x4){0.f, 0.f, 0.f, 0.f};
#pragma unroll
    for (int kc = 0; kc < 2; ++kc) {
        short8v aH = gfrag(xg, w, kc, l);
#pragma unroll
        for (int ct = 0; ct < 4; ++ct) {
            acc[ct] = MFMA(aH, ldfrag(yh, ct, kc, l), acc[ct]);
            acc[ct] = MFMA(aH, ldfrag(yl, ct, kc, l), acc[ct]);
        }
    }
}

// D = X·Y^T, X split hi/lo LDS, Y hi-only LDS  (out = A·z4^T)
__device__ __forceinline__ void p2a(const short* xh, const short* xl,
                                    const short* yh,
                                    int w, int l, f32x4 (&acc)[4]) {
#pragma unroll
    for (int ct = 0; ct < 4; ++ct) acc[ct] = (f32x4){0.f, 0.f, 0.f, 0.f};
#pragma unroll
    for (int kc = 0; kc < 2; ++kc) {
        short8v aH = ldfrag(xh, w, kc, l);
        short8v aL = ldfrag(xl, w, kc, l);
#pragma unroll
        for (int ct = 0; ct < 4; ++ct) {
            short8v bH = ldfrag(yh, ct, kc, l);
            acc[ct] = MFMA(aH, bH, acc[ct]);
            acc[ct] = MFMA(aL, bH, acc[ct]);
        }
    }
}

// pack-store D transposed, hi only: z[n][m] = bf16(D[m][n])
__device__ __forceinline__ void pack1(const f32x4 (&acc)[4], short* zh, int w, int l) {
    int m0 = w * 16 + (l >> 4) * 4;
#pragma unroll
    for (int ct = 0; ct < 4; ++ct) {
        int n = ct * 16 + (l & 15);
        short4v h;
#pragma unroll
        for (int r = 0; r < 4; ++r) h[r] = f2bf(acc[ct][r]);
        *(short4v*)&zh[n * PITCH + m0] = h;
    }
}

// in-place exact transpose of ONE plane via identity-MFMA (1 internal barrier)
__device__ __forceinline__ void idtrans_ip1(short* pa, int w, int l) {
    short8v a0 = ldfrag(pa, w, 0, l);
    short8v a1 = ldfrag(pa, w, 1, l);
    short8v I0, I1;
#pragma unroll
    for (int j = 0; j < 8; ++j) {
        int bit = 8 * (l >> 4) + j;
        I0[j] = (bit == (l & 15))      ? (short)0x3F80 : (short)0;
        I1[j] = (bit == (l & 15) + 16) ? (short)0x3F80 : (short)0;
    }
    __syncthreads();
    int m0 = w * 16 + (l >> 4) * 4;
    const f32x4 z4 = {0.f, 0.f, 0.f, 0.f};
#pragma unroll
    for (int s = 0; s < 4; ++s) {
        f32x4 d = MFMA((s >> 1) ? a1 : a0, (s & 1) ? I1 : I0, z4);
        short4v ha;
#pragma unroll
        for (int r = 0; r < 4; ++r) ha[r] = f2bf(d[r]);   // exact: values are bf16
        *(short4v*)&pa[(s * 16 + (l & 15)) * PITCH + m0] = ha;
    }
}

// ---------------- K0: inv_diag ------------------------------------------------
__global__ __launch_bounds__(256) void k0_invdiag(const float* __restrict__ x,
                                                  float* __restrict__ invd) {
    int t = blockIdx.x * 256 + threadIdx.x;
    int nc = t >> 6, k = t & 63;
    float v = fabsf(x[(size_t)nc * 4096 + (size_t)k * 65]);
    invd[t] = rsqrtf(fmaxf(v, 1e-4f));
}

// ---------------- K0b: w3T[co][c] = concat(wq,wk,wv)^T, bf16 hi ---------------
__global__ __launch_bounds__(256) void k0b_w3(const float* __restrict__ wq,
                                              const float* __restrict__ wk,
                                              const float* __restrict__ wv,
                                              short* __restrict__ w3h) {
    int idx = blockIdx.x * 256 + threadIdx.x;   // [0, 12288)
    int co = idx >> 6, c = idx & 63;
    const float* w = (co < 64) ? wq : (co < 128) ? wk : wv;
    w3h[idx] = f2bf(w[c * 64 + (co & 63)]);
}

// ---------------- K1: cov2cor + channel mixing via MFMA (hi-only) -------------
// Block (n,i): D[j][co] = sum_c corT[j][c] * w3T[co][c]; LDS z-stage for
// coalesced 128B-per-row global writes (R5 lesson: direct reg stores = 2.2x WRITE).
__global__ __launch_bounds__(256, 5) void k1_mix_mfma(
    const float* __restrict__ x, const float* __restrict__ invd,
    const short* __restrict__ w3h,
    short* __restrict__ Qh, short* __restrict__ Kh, short* __restrict__ Vh)
{
    __shared__ __align__(16) short zbuf[13824];   // z[192][72]; rows 0..63 alias cor
    short* ch = zbuf;                             // cor hi [64][72]

    const int b = blockIdx.x, n = b >> 6, i = b & 63;
    const int t = threadIdx.x, l = t & 63, w = t >> 6;
    const size_t nbase = (size_t)n * 64;

    // stage cor hi plane [c][j]
#pragma unroll
    for (int rep = 0; rep < 4; ++rep) {
        int id = rep * 256 + t;                 // 1024 float4 chunks
        int c = id >> 4, j4 = (id & 15) * 4;
        float4 xv = *(const float4*)&x[((nbase + c) * 64 + i) * 64 + j4];
        float ii = invd[(nbase + c) * 64 + i];
        float4 jv = *(const float4*)&invd[(nbase + c) * 64 + j4];
        float vv[4] = {xv.x * ii * jv.x, xv.y * ii * jv.y,
                       xv.z * ii * jv.z, xv.w * ii * jv.w};
        short4v h;
#pragma unroll
        for (int r = 0; r < 4; ++r)
            h[r] = f2bf(fminf(1.0f, fmaxf(-1.0f, vv[r])));
        *(short4v*)&ch[c * PITCH + j4] = h;
    }
    __syncthreads();
    idtrans_ip1(ch, w, l);       // cor -> corT in place (1 internal barrier)
    __syncthreads();

    // wave w: co-tiles ct = 3w..3w+2, all 4 j-tiles
    f32x4 acc[4][3];
#pragma unroll
    for (int jt = 0; jt < 4; ++jt)
#pragma unroll
        for (int cc = 0; cc < 3; ++cc) acc[jt][cc] = (f32x4){0.f, 0.f, 0.f, 0.f};
#pragma unroll
    for (int kc = 0; kc < 2; ++kc) {
#pragma unroll
        for (int cc = 0; cc < 3; ++cc) {
            short8v bH = gfrag(w3h, w * 3 + cc, kc, l);
#pragma unroll
            for (int jt = 0; jt < 4; ++jt) {
                short8v aH = ldfrag(ch, jt, kc, l);
                acc[jt][cc] = MFMA(aH, bH, acc[jt][cc]);
            }
        }
    }
    __syncthreads();   // all reads of ch done; zbuf free

    // pack transposed into z[co3][j] (hi only)
    {
        int m0 = (l >> 4) * 4, nb = l & 15;
#pragma unroll
        for (int cc = 0; cc < 3; ++cc) {
            int nrow = (w * 3 + cc) * 16 + nb;
#pragma unroll
            for (int jt = 0; jt < 4; ++jt) {
                short4v h;
#pragma unroll
                for (int r = 0; r < 4; ++r) h[r] = f2bf(acc[jt][cc][r]);
                *(short4v*)&zbuf[nrow * PITCH + jt * 16 + m0] = h;
            }
        }
    }
    __syncthreads();

    // coalesced copy out: rows 0..63 Q, 64..127 K, 128..191 V (uniform per rep)
#pragma unroll
    for (int rep = 0; rep < 12; ++rep) {
        int id = rep * 256 + t;                 // 3072 chunks of 4 shorts
        int row = id >> 4, j4 = (id & 15) * 4;
        short4v v = *(short4v*)&zbuf[row * PITCH + j4];
        if (rep < 4) {
            *(short4v*)&Qh[(nbase + row) * 4096 + (size_t)i * 64 + j4] = v;
        } else if (rep < 8) {
            *(short4v*)&Kh[(nbase + row - 64) * 4096 + (size_t)i * 64 + j4] = v;
        } else {
            *(short4v*)&Vh[(nbase + row - 128) * 4096 + (size_t)i * 64 + j4] = v;
        }
    }
}

// ---------------- K2: per-(n,c) attention chain -------------------------------
// Q,K,V,Z1,z4 hi-only; A split hi/lo (only the post-exp factor matters).
__global__ __launch_bounds__(256, 5) void k2_attn_mfma(
    const float* __restrict__ x,
    const short* __restrict__ Qh, const short* __restrict__ Kh,
    const short* __restrict__ Vh,
    float* __restrict__ out)
{
    // P0: K->Kt->Al ; P1: Z1->Ah ; P2: z4
    __shared__ __align__(16) short P[3][4608];
    __shared__ float part[4][64];
    __shared__ float invs[64];
    __shared__ float red[4];

    const int t = threadIdx.x, l = t & 63, w = t >> 6;
    const int nc = blockIdx.x;
    const size_t gbase = (size_t)nc * 4096;

    const short* qh = Qh + gbase;
    const short* kh = Kh + gbase;
    const short* vh = Vh + gbase;

    // stage K hi
#pragma unroll
    for (int rep = 0; rep < 4; ++rep) {
        int id = rep * 256 + t;
        int r = id >> 4, c4 = (id & 15) * 4;
        *(short4v*)&P[0][r * PITCH + c4] = *(const short4v*)&kh[r * 64 + c4];
    }
    __syncthreads();

    idtrans_ip1(P[0], w, l);   // K -> Kt in place
    __syncthreads();

    f32x4 acc[4];

    // Z1 = Q(global) · Kt^T  -> pack into P1
    p1_g(qh, P[0], w, l, acc);
    pack1(acc, P[1], w, l);
    __syncthreads();

    // Pt = Z1 · Kt^T (in registers)
    p1(P[1], P[0], w, l, acc);

    // ---- soft_pd_max ----
    float mx = -1e30f;
#pragma unroll
    for (int ct = 0; ct < 4; ++ct)
#pragma unroll
        for (int r = 0; r < 4; ++r) mx = fmaxf(mx, acc[ct][r]);
#pragma unroll
    for (int off = 1; off < 64; off <<= 1) mx = fmaxf(mx, __shfl_xor(mx, off));
    if (l == 0) red[w] = mx;
    __syncthreads();
    mx = fmaxf(fmaxf(red[0], red[1]), fmaxf(red[2], red[3]));

    float e[4][4];
    float cs[4];
#pragma unroll
    for (int ct = 0; ct < 4; ++ct) {
        float s = 0.f;
#pragma unroll
        for (int r = 0; r < 4; ++r) {
            float ev = __expf(acc[ct][r] - mx);
            e[ct][r] = ev;
            s += ev;
        }
        cs[ct] = s;
    }
#pragma unroll
    for (int ct = 0; ct < 4; ++ct) {
        cs[ct] += __shfl_xor(cs[ct], 16);
        cs[ct] += __shfl_xor(cs[ct], 32);
    }
    if (l < 16) {
#pragma unroll
        for (int ct = 0; ct < 4; ++ct) part[w][ct * 16 + l] = cs[ct];
    }
    __syncthreads();
    if (t < 64) {
        float dia = part[0][t] + part[1][t] + part[2][t] + part[3][t];
        float tot = dia;
#pragma unroll
        for (int off = 1; off < 64; off <<= 1) tot += __shfl_xor(tot, off);
        dia = fmaxf(dia, tot / 100000.0f);
        dia = fmaxf(dia, 1e-5f);
        invs[t] = rsqrtf(dia);
    }
    __syncthreads();

    // A[m][n] = e*inv*inv -> hi P1, lo P0 (Z1,Kt dead; softmax barriers fence)
    {
        int m0 = w * 16 + (l >> 4) * 4;
        float ir[4] = {invs[m0], invs[m0 + 1], invs[m0 + 2], invs[m0 + 3]};
        int nb = l & 15;
#pragma unroll
        for (int ct = 0; ct < 4; ++ct) {
            float ic = invs[ct * 16 + nb];
            short4v h, lo;
#pragma unroll
            for (int r = 0; r < 4; ++r) {
                float v = e[ct][r] * ir[r] * ic;
                short hb = f2bf(v);
                h[r]  = hb;
                lo[r] = f2bf(v - bf2f(hb));
            }
            *(short4v*)&P[1][(ct * 16 + nb) * PITCH + m0] = h;
            *(short4v*)&P[0][(ct * 16 + nb) * PITCH + m0] = lo;
        }
    }
    __syncthreads();

    // z4 = V(global) · A^T -> pack into P2
    p2v_g(vh, P[1], P[0], w, l, acc);
    pack1(acc, P[2], w, l);
    __syncthreads();

    // OUT = A · z4^T = A V A^T
    p2a(P[1], P[0], P[2], w, l, acc);
    __syncthreads();   // all plane reads done; alias as f32 out-stage

    // stage out tile f32 [64][68], then vectorized residual+store
    {
        float* ofs = (float*)&P[0][0];
        int m0 = w * 16 + (l >> 4) * 4;
        int nb = l & 15;
#pragma unroll
        for (int ct = 0; ct < 4; ++ct)
#pragma unroll
            for (int r = 0; r < 4; ++r)
                ofs[(m0 + r) * 68 + ct * 16 + nb] = acc[ct][r];
    }
    __syncthreads();
    {
        const float* ofs = (const float*)&P[0][0];
#pragma unroll
        for (int rep = 0; rep < 4; ++rep) {
            int id = rep * 256 + t;
            int row = id >> 4, c4 = (id & 15) * 4;
            float4 v  = *(const float4*)&ofs[row * 68 + c4];
            float4 xv = *(const float4*)&x[gbase + (size_t)row * 64 + c4];
            *(float4*)&out[gbase + (size_t)row * 64 + c4] =
                make_float4(xv.x + v.x, xv.y + v.y, xv.z + v.z, xv.w + v.w);
        }
    }
}

// ---------------- launch -----------------------------------------------------
extern "C" void kernel_launch(void* const* d_in, const int* in_sizes, int n_in,
                              void* d_out, int out_size, void* d_ws, size_t ws_size,
                              hipStream_t stream) {
    const float* x  = (const float*)d_in[0];
    const float* wq = (const float*)d_in[1];
    const float* wk = (const float*)d_in[2];
    const float* wv = (const float*)d_in[3];
    float* out = (float*)d_out;

    char* wsb = (char*)d_ws;
    float* invd = (float*)wsb;                       // 1 MB
    short* w3h  = (short*)(wsb + (1 << 20));         // 24 KB
    short* Qh   = (short*)(wsb + (2 << 20));         // 32 MB
    short* Kh   = Qh + 16777216;                     // 32 MB
    short* Vh   = Kh + 16777216;                     // 32 MB (total 98 MB)

    k0_invdiag<<<1024, 256, 0, stream>>>(x, invd);
    k0b_w3<<<48, 256, 0, stream>>>(wq, wk, wv, w3h);
    k1_mix_mfma<<<4096, 256, 0, stream>>>(x, invd, w3h, Qh, Kh, Vh);
    k2_attn_mfma<<<4096, 256, 0, stream>>>(x, Qh, Kh, Vh, out);
}